// Round 10
// baseline (30728.906 us; speedup 1.0000x reference)
//
#include <hip/hip_runtime.h>

#define Tn 512
#define Bn 256
#define Hn 512
#define INn 512
#define TPB 512
#define RG 16              // batch rows per group
#define CB 64              // output cols per block
#define BnHn (Bn * Hn)

typedef __attribute__((ext_vector_type(8))) short bf16x8;
typedef __attribute__((ext_vector_type(4))) float f32x4;
typedef unsigned long long ull;
typedef unsigned short us;

__device__ __forceinline__ us f2bf(float f) {
  unsigned int u = __float_as_uint(f);
  return (us)((u + 0x7fffu + ((u >> 16) & 1u)) >> 16);
}
__device__ __forceinline__ float bf2f(us u) {
  return __uint_as_float(((unsigned int)u) << 16);
}
__device__ __forceinline__ float sigm(float x) { return 1.0f / (1.0f + __expf(-x)); }
__device__ __forceinline__ float tanh_f(float x) { return 2.0f / (1.0f + __expf(-2.0f * x)) - 1.0f; }
__device__ __forceinline__ bf16x8 ld8(const us* p) { return *reinterpret_cast<const bf16x8*>(p); }

// agent-scope (LLC) relaxed ops — proven r3/r4/r8/r9
__device__ __forceinline__ ull ald8(const us* p) {
  return __hip_atomic_load((const ull*)p, __ATOMIC_RELAXED, __HIP_MEMORY_SCOPE_AGENT);
}
__device__ __forceinline__ void ast4(us* p, unsigned int v) {
  __hip_atomic_store((unsigned int*)p, v, __ATOMIC_RELAXED, __HIP_MEMORY_SCOPE_AGENT);
}
__device__ __forceinline__ unsigned int aldf(const unsigned int* p) {
  return __hip_atomic_load(p, __ATOMIC_RELAXED, __HIP_MEMORY_SCOPE_AGENT);
}
__device__ __forceinline__ void astf(unsigned int* p, unsigned int v) {
  __hip_atomic_store(p, v, __ATOMIC_RELAXED, __HIP_MEMORY_SCOPE_AGENT);
}
__device__ __forceinline__ f32x4 mfma16(bf16x8 a, bf16x8 b, f32x4 c) {
  return __builtin_amdgcn_mfma_f32_16x16x32_bf16(a, b, c, 0, 0, 0);
}

// ---------------- fp32 -> bf16 conversion ----------------
__global__ __launch_bounds__(256) void cvt_kernel(const float* __restrict__ in,
                                                  us* __restrict__ out, int n) {
  const int stride = gridDim.x * blockDim.x * 4;
  for (int i = (blockIdx.x * blockDim.x + threadIdx.x) * 4; i < n; i += stride) {
    float4 v = *reinterpret_cast<const float4*>(in + i);
    ushort4 o;
    o.x = f2bf(v.x); o.y = f2bf(v.y); o.z = f2bf(v.z); o.w = f2bf(v.w);
    *reinterpret_cast<ushort4*>(out + i) = o;
  }
}

// ---------------- one gate GEMM: out[16rows x 64cols] = A(16x512) @ W(64x512)^T ----------------
__device__ __forceinline__ void gemm_gate(const us* As, const us* W, int rowbase,
                                          float (*po)[CB + 1], int lane, int swzA) {
  const int l15 = lane & 15;
  const int lk = (lane >> 4) * 8;
  const us* wp = W + (size_t)(rowbase + l15) * Hn + lk;
  f32x4 a0 = {}, a1 = {}, a2 = {}, a3 = {};
#pragma unroll
  for (int kt = 0; kt < 16; ++kt) {
    const int k2 = (kt * 32 + lk) * 2;
    bf16x8 a = *reinterpret_cast<const bf16x8*>(
        reinterpret_cast<const char*>(As) + l15 * 1024 + (k2 ^ swzA));
    a0 = mfma16(a, ld8(wp + kt * 32), a0);
    a1 = mfma16(a, ld8(wp + 16 * Hn + kt * 32), a1);
    a2 = mfma16(a, ld8(wp + 32 * Hn + kt * 32), a2);
    a3 = mfma16(a, ld8(wp + 48 * Hn + kt * 32), a3);
  }
  const int r0 = (lane >> 4) * 4;
#pragma unroll
  for (int r = 0; r < 4; ++r) {
    po[r0 + r][l15] = a0[r];
    po[r0 + r][16 + l15] = a1[r];
    po[r0 + r][32 + l15] = a2[r];
    po[r0 + r][48 + l15] = a3[r];
  }
}

// ---------------- XP tile (one gate, one timestep): bias-folded, bf16 out ----------------
__device__ __forceinline__ void xp_tile(const us* __restrict__ xb, const us* __restrict__ Wxb,
                                        const float* __restrict__ bx, const float* __restrict__ bh,
                                        const float* __restrict__ bgh, us* dst, int tl,
                                        int b0, int j0, int gate, int lane) {
  const int l15 = lane & 15;
  const int lk = (lane >> 4) * 8;
  const us* ap = xb + ((size_t)tl * Bn + b0 + l15) * INn + lk;
  const us* wp = Wxb + (size_t)(gate * 512 + j0 + l15) * INn + lk;
  f32x4 a0 = {}, a1 = {}, a2 = {}, a3 = {};
#pragma unroll
  for (int kt = 0; kt < 16; ++kt) {
    bf16x8 a = ld8(ap + kt * 32);
    a0 = mfma16(a, ld8(wp + kt * 32), a0);
    a1 = mfma16(a, ld8(wp + 16 * INn + kt * 32), a1);
    a2 = mfma16(a, ld8(wp + 32 * INn + kt * 32), a2);
    a3 = mfma16(a, ld8(wp + 48 * INn + kt * 32), a3);
  }
  const int r0 = (lane >> 4) * 4;
#pragma unroll
  for (int ct = 0; ct < 4; ++ct) {
    const int col = j0 + ct * 16 + l15;
    float bias = bx[gate * 512 + col];
    if (gate == 0) bias += bh[col] + bgh[col];
    else if (gate == 1) bias += bh[512 + col] + bgh[512 + col];
    else if (gate == 3) bias += bh[1024 + col] + bgh[1024 + col];
    const f32x4 ac = (ct == 0) ? a0 : (ct == 1) ? a1 : (ct == 2) ? a2 : a3;
#pragma unroll
    for (int r = 0; r < 4; ++r)
      dst[gate * 1024 + (r0 + r) * CB + ct * 16 + l15] = f2bf(ac[r] + bias);
  }
}

// ---------------- persistent recurrence ----------------
// 128 blocks: grp = blockIdx&15 (16 rows), jblk = blockIdx>>4 (64 cols). All
// blocks of a group land on one XCD (idx mod 8 constant). hd computed locally
// from retained h(t-1) (no hd exchange). Single hb/gb buffers (flag-ordered).
__global__ __launch_bounds__(512, 1) void persist_kernel(
    const us* __restrict__ Whb, const us* __restrict__ Wghb,
    const us* __restrict__ Whdb, const us* __restrict__ Wgb,
    const us* __restrict__ xb, const us* __restrict__ Wxb,
    const float* __restrict__ bx, const float* __restrict__ bh,
    const float* __restrict__ bgh, const float* __restrict__ bhd,
    const float* __restrict__ bg,
    us* __restrict__ hb, us* __restrict__ gb,
    float* __restrict__ g_master,
    const float* __restrict__ h0, const float* __restrict__ g0,
    float* __restrict__ hs, float* __restrict__ h_tail, float* __restrict__ g_tail,
    unsigned int* __restrict__ slab,  // per grp: [grp*32..+15]=FH, [+16..+31]=FG
    int t0, int Tc) {
  __shared__ us As_h[2][RG * 512];     // 2 x 16KB: h(t) / h(t-1)
  __shared__ us As_B[RG * 512];        // 16KB: hd (X) / g (Y)
  __shared__ float pa[8][RG][CB + 1];  // 32.5KB
  __shared__ us xp_ls[2][4 * RG * CB]; // 2 x 8KB

  const int tid = threadIdx.x;
  const int grp = blockIdx.x & 15;
  const int jblk = blockIdx.x >> 4;
  const int j0 = jblk * CB;
  const int b0 = grp * RG;
  const int wv = tid >> 6;
  const int lane = tid & 63;
  const int l15 = lane & 15;
  const int swzA = (l15 & 7) << 4;
  unsigned int* FH = slab + grp * 32;
  unsigned int* FG = FH + 16;

  // elementwise mapping: 2 consecutive cols per thread
  const int bl_e = tid >> 5;
  const int jl0 = (tid & 31) * 2;
  const int j_e = j0 + jl0;
  const size_t o_e = (size_t)(b0 + bl_e) * Hn + j_e;

  float h_m[2], g_m[2], z2p[2], r2p[2], bz2[2], br2[2], bgc2[2];
  {
    const float* hsrc0 = (t0 == 0) ? h0 : hs + (size_t)(t0 - 1) * BnHn;
    const float* gsrc0 = (t0 == 0) ? g0 : g_master;
    h_m[0] = hsrc0[o_e]; h_m[1] = hsrc0[o_e + 1];
    g_m[0] = gsrc0[o_e]; g_m[1] = gsrc0[o_e + 1];
  }
#pragma unroll
  for (int e = 0; e < 2; ++e) {
    const int j = j_e + e;
    bz2[e] = bhd[j] + bg[j];
    br2[e] = bhd[512 + j] + bg[512 + j];
    bgc2[e] = bhd[1024 + j];
  }

  // ---- prologue XP(t0)->buf0, XP(t0+1)->buf1 (one gate per wave) ----
  if (wv < 4) xp_tile(xb, Wxb, bx, bh, bgh, xp_ls[0], 0, b0, j0, wv, lane);
  else if (Tc > 1) xp_tile(xb, Wxb, bx, bh, bgh, xp_ls[1], 1, b0, j0, wv - 4, lane);

  // ---- prologue state gathers from fp32 sources (no cross-block race) ----
  {
    const float* hsrc = (t0 == 0) ? h0 : hs + (size_t)(t0 - 1) * BnHn;
    const float* gsrc = (t0 == 0) ? g0 : g_master;
#pragma unroll
    for (int q = 0; q < 4; ++q) {
      const int f = tid + q * 512;
      const int rr = f >> 7, c8 = f & 127;
      const int byte = rr * 1024 + ((c8 * 8) ^ ((rr & 7) << 4));
      float4 hv = *reinterpret_cast<const float4*>(hsrc + (size_t)(b0 + rr) * Hn + c8 * 4);
      float4 gv = *reinterpret_cast<const float4*>(gsrc + (size_t)(b0 + rr) * Hn + c8 * 4);
      ull hu = (ull)f2bf(hv.x) | ((ull)f2bf(hv.y) << 16) | ((ull)f2bf(hv.z) << 32) |
               ((ull)f2bf(hv.w) << 48);
      ull gu = (ull)f2bf(gv.x) | ((ull)f2bf(gv.y) << 16) | ((ull)f2bf(gv.z) << 32) |
               ((ull)f2bf(gv.w) << 48);
      *reinterpret_cast<ull*>(reinterpret_cast<char*>(As_h[1]) + byte) = hu;
      *reinterpret_cast<ull*>(reinterpret_cast<char*>(As_B) + byte) = gu;
    }
  }
  __syncthreads();
  // prologue GEMMs: wv0-2 Wh·h, wv3-5 Wgh·g, wv6-7 Wg·g
  if (wv < 3) gemm_gate(As_h[1], Whb, wv * 512 + j0, pa[wv], lane, swzA);
  else if (wv < 6) gemm_gate(As_B, Wghb, (wv - 3) * 512 + j0, pa[wv], lane, swzA);
  else gemm_gate(As_B, Wgb, (wv - 6) * 512 + j0, pa[wv], lane, swzA);
  __syncthreads();
  // h-update(t0) + publish
#pragma unroll
  for (int e = 0; e < 2; ++e) {
    const int jl = jl0 + e;
    const int xo = bl_e * CB + jl;
    const float z = sigm(bf2f(xp_ls[0][xo]) + pa[0][bl_e][jl] + pa[3][bl_e][jl]);
    const float r = sigm(bf2f(xp_ls[0][1024 + xo]) + pa[1][bl_e][jl] + pa[4][bl_e][jl]);
    const float u = sigm(bf2f(xp_ls[0][3072 + xo]) + pa[2][bl_e][jl] + pa[5][bl_e][jl]);
    const float cand = tanh_f(bf2f(xp_ls[0][2048 + xo]) + r * h_m[e] + u * g_m[e]);
    h_m[e] = (1.0f - z) * h_m[e] + z * cand;
    z2p[e] = pa[6][bl_e][jl];
    r2p[e] = pa[7][bl_e][jl];
  }
  ast4(hb + o_e, (unsigned int)f2bf(h_m[0]) | ((unsigned int)f2bf(h_m[1]) << 16));
  __syncthreads();
  if (tid == 0) astf(FH + jblk, 1u);
  {
    float2 hv = {h_m[0], h_m[1]};
    *reinterpret_cast<float2*>(hs + (size_t)t0 * BnHn + o_e) = hv;
    if (t0 == Tn - 1) *reinterpret_cast<float2*>(h_tail + o_e) = hv;
  }

  // ================= main loop =================
  for (int tt = 0; tt < Tc; ++tt) {
    const int t = t0 + tt;
    const int cur = tt & 1, prv = cur ^ 1;

    // -------- X(tt): gather h(t), local hd, GEMMs, g-update --------
    if (lane < 8) {
      const unsigned int* p = FH + lane;
      while (aldf(p) < (unsigned int)(tt + 1)) __builtin_amdgcn_s_sleep(1);
    }
#pragma unroll
    for (int q = 0; q < 4; ++q) {
      const int f = tid + q * 512;
      const int rr = f >> 7, c8 = f & 127;
      const int byte = rr * 1024 + ((c8 * 8) ^ ((rr & 7) << 4));
      *reinterpret_cast<ull*>(reinterpret_cast<char*>(As_h[cur]) + byte) =
          ald8(hb + (size_t)(b0 + rr) * Hn + c8 * 4);
    }
    __syncthreads();
    // hd = h(t) - h(t-1), elementwise in swizzled layout
#pragma unroll
    for (int q = 0; q < 4; ++q) {
      const int f = tid + q * 512;
      const int rr = f >> 7, c8 = f & 127;
      const int byte = rr * 1024 + ((c8 * 8) ^ ((rr & 7) << 4));
      const ull va = *reinterpret_cast<const ull*>(reinterpret_cast<const char*>(As_h[cur]) + byte);
      const ull vb = *reinterpret_cast<const ull*>(reinterpret_cast<const char*>(As_h[prv]) + byte);
      ull o = 0;
#pragma unroll
      for (int i = 0; i < 4; ++i) {
        const float d = bf2f((us)(va >> (16 * i))) - bf2f((us)(vb >> (16 * i)));
        o |= (ull)f2bf(d) << (16 * i);
      }
      *reinterpret_cast<ull*>(reinterpret_cast<char*>(As_B) + byte) = o;
    }
    __syncthreads();
    if (wv < 3) gemm_gate(As_h[cur], Whb, wv * 512 + j0, pa[wv], lane, swzA);
    else if (wv < 6) gemm_gate(As_B, Whdb, (wv - 3) * 512 + j0, pa[wv], lane, swzA);
    else if (tt + 2 < Tc)  // XP(t+2) gates 0,1
      xp_tile(xb, Wxb, bx, bh, bgh, xp_ls[cur], tt + 2, b0, j0, wv - 6, lane);
    __syncthreads();
#pragma unroll
    for (int e = 0; e < 2; ++e) {
      const int jl = jl0 + e;
      const float z2 = sigm(pa[3][bl_e][jl] + z2p[e] + bz2[e]);
      const float r2 = sigm(pa[4][bl_e][jl] + r2p[e] + br2[e]);
      const float gc = tanh_f(pa[5][bl_e][jl] + bgc2[e] + r2 * g_m[e]);
      g_m[e] = (1.0f - z2) * g_m[e] + z2 * gc;
    }
    ast4(gb + o_e, (unsigned int)f2bf(g_m[0]) | ((unsigned int)f2bf(g_m[1]) << 16));
    __syncthreads();
    if (tid == 0) astf(FG + jblk, (unsigned int)(tt + 1));
    if (t == Tn - 1) {
      float2 gv = {g_m[0], g_m[1]};
      *reinterpret_cast<float2*>(g_tail + o_e) = gv;
    }
    if (tt + 1 >= Tc) break;

    // -------- Y(tt): gather g(t), GEMMs, h-update(t+1) --------
    if (lane < 8) {
      const unsigned int* p = FG + lane;
      while (aldf(p) < (unsigned int)(tt + 1)) __builtin_amdgcn_s_sleep(1);
    }
#pragma unroll
    for (int q = 0; q < 4; ++q) {
      const int f = tid + q * 512;
      const int rr = f >> 7, c8 = f & 127;
      const int byte = rr * 1024 + ((c8 * 8) ^ ((rr & 7) << 4));
      *reinterpret_cast<ull*>(reinterpret_cast<char*>(As_B) + byte) =
          ald8(gb + (size_t)(b0 + rr) * Hn + c8 * 4);
    }
    __syncthreads();
    if (wv < 3) gemm_gate(As_B, Wghb, wv * 512 + j0, pa[3 + wv], lane, swzA);
    else if (wv == 3) gemm_gate(As_B, Wgb, j0, pa[6], lane, swzA);
    else if (wv == 4) gemm_gate(As_B, Wgb, 512 + j0, pa[7], lane, swzA);
    else if (wv < 7 && tt + 2 < Tc)  // XP(t+2) gates 2,3
      xp_tile(xb, Wxb, bx, bh, bgh, xp_ls[cur], tt + 2, b0, j0, wv - 3, lane);
    __syncthreads();
#pragma unroll
    for (int e = 0; e < 2; ++e) {
      const int jl = jl0 + e;
      const int xo = bl_e * CB + jl;
      const float z = sigm(bf2f(xp_ls[prv][xo]) + pa[0][bl_e][jl] + pa[3][bl_e][jl]);
      const float r = sigm(bf2f(xp_ls[prv][1024 + xo]) + pa[1][bl_e][jl] + pa[4][bl_e][jl]);
      const float u = sigm(bf2f(xp_ls[prv][3072 + xo]) + pa[2][bl_e][jl] + pa[5][bl_e][jl]);
      const float cand = tanh_f(bf2f(xp_ls[prv][2048 + xo]) + r * h_m[e] + u * g_m[e]);
      h_m[e] = (1.0f - z) * h_m[e] + z * cand;
      z2p[e] = pa[6][bl_e][jl];
      r2p[e] = pa[7][bl_e][jl];
    }
    ast4(hb + o_e, (unsigned int)f2bf(h_m[0]) | ((unsigned int)f2bf(h_m[1]) << 16));
    __syncthreads();
    if (tid == 0) astf(FH + jblk, (unsigned int)(tt + 2));
    {
      float2 hv = {h_m[0], h_m[1]};
      *reinterpret_cast<float2*>(hs + (size_t)(t + 1) * BnHn + o_e) = hv;
      if (t + 1 == Tn - 1) *reinterpret_cast<float2*>(h_tail + o_e) = hv;
    }
  }
  {
    float2 gv = {g_m[0], g_m[1]};
    *reinterpret_cast<float2*>(g_master + o_e) = gv;
  }
}

// ---------------- host ----------------
extern "C" void kernel_launch(void* const* d_in, const int* in_sizes, int n_in,
                              void* d_out, int out_size, void* d_ws, size_t ws_size,
                              hipStream_t stream) {
  const float* x   = (const float*)d_in[0];
  const float* h0  = (const float*)d_in[1];
  const float* g0  = (const float*)d_in[2];
  const float* Wx  = (const float*)d_in[3];
  const float* bx  = (const float*)d_in[4];
  const float* Wh  = (const float*)d_in[5];
  const float* bh  = (const float*)d_in[6];
  const float* Wgh = (const float*)d_in[7];
  const float* bgh = (const float*)d_in[8];
  const float* Whd = (const float*)d_in[9];
  const float* bhd = (const float*)d_in[10];
  const float* Wg  = (const float*)d_in[11];
  const float* bg  = (const float*)d_in[12];

  char* ws = (char*)d_ws;
  us* Whb  = (us*)(ws + 0);                // 1536x512
  us* Wghb = (us*)(ws + 1572864);
  us* Whdb = (us*)(ws + 3145728);
  us* Wgb  = (us*)(ws + 4718592);          // 1024x512
  us* Wxb  = (us*)(ws + 5767168);          // 2048x512
  us* hb   = (us*)(ws + 7864320);          // 256x512 bf16
  us* gb_  = (us*)(ws + 8126464);          // 256x512 bf16
  float* g_master     = (float*)(ws + 8388608);   // 256x512 f32
  unsigned int* flags = (unsigned int*)(ws + 8912896);  // 2KB
  const size_t FIXED = 8916992ULL;

  int Tc = 512;
  while (Tc > 1 && FIXED + (size_t)Tc * 262144ULL > ws_size) Tc >>= 1;
  us* xb = (us*)(ws + FIXED);  // (Tc,256,512) bf16

  float* hs = (float*)d_out;
  float* h_tail = hs + (size_t)Tn * Bn * Hn;
  float* g_tail = h_tail + (size_t)Bn * Hn;

  cvt_kernel<<<dim3(512), 256, 0, stream>>>(Wh, Whb, 1536 * 512);
  cvt_kernel<<<dim3(512), 256, 0, stream>>>(Wgh, Wghb, 1536 * 512);
  cvt_kernel<<<dim3(512), 256, 0, stream>>>(Whd, Whdb, 1536 * 512);
  cvt_kernel<<<dim3(512), 256, 0, stream>>>(Wg, Wgb, 1024 * 512);
  cvt_kernel<<<dim3(512), 256, 0, stream>>>(Wx, Wxb, 2048 * 512);

  const int nChunks = Tn / Tc;
  for (int c = 0; c < nChunks; ++c) {
    const int t0 = c * Tc;
    hipMemsetAsync(flags, 0, 2048, stream);
    cvt_kernel<<<dim3(2048), 256, 0, stream>>>(x + (size_t)t0 * Bn * INn, xb,
                                               Tc * Bn * INn);
    persist_kernel<<<dim3(128), dim3(TPB), 0, stream>>>(
        Whb, Wghb, Whdb, Wgb, xb, Wxb, bx, bh, bgh, bhd, bg, hb, gb_,
        g_master, h0, g0, hs, h_tail, g_tail, flags, t0, Tc);
  }
}

// Round 13
// 10442.012 us; speedup vs baseline: 2.9428x; 2.9428x over previous
//
#include <hip/hip_runtime.h>

#define Tn 512
#define Bn 256
#define Hn 512
#define INn 512
#define TPB 512
#define BnHn (Bn * Hn)

typedef __attribute__((ext_vector_type(8))) short bf16x8;
typedef __attribute__((ext_vector_type(4))) float f32x4;
typedef unsigned long long ull;
typedef unsigned short us;

__device__ __forceinline__ us f2bf(float f) {
  unsigned int u = __float_as_uint(f);
  return (us)((u + 0x7fffu + ((u >> 16) & 1u)) >> 16);
}
__device__ __forceinline__ float bf2f(us u) {
  return __uint_as_float(((unsigned int)u) << 16);
}
__device__ __forceinline__ float sigm(float x) { return 1.0f / (1.0f + __expf(-x)); }
__device__ __forceinline__ float tanh_f(float x) { return 2.0f / (1.0f + __expf(-2.0f * x)) - 1.0f; }
__device__ __forceinline__ bf16x8 ld8(const us* p) { return *reinterpret_cast<const bf16x8*>(p); }

// ---- agent-scope (LLC) relaxed ops — proven r3/r4/r8/r9/r10 (intra-XCD groups) ----
__device__ __forceinline__ ull ald8(const us* p) {
  return __hip_atomic_load((const ull*)p, __ATOMIC_RELAXED, __HIP_MEMORY_SCOPE_AGENT);
}
__device__ __forceinline__ void ast4(us* p, unsigned int v) {
  __hip_atomic_store((unsigned int*)p, v, __ATOMIC_RELAXED, __HIP_MEMORY_SCOPE_AGENT);
}
__device__ __forceinline__ unsigned int aldf(const unsigned int* p) {
  return __hip_atomic_load(p, __ATOMIC_RELAXED, __HIP_MEMORY_SCOPE_AGENT);
}
__device__ __forceinline__ void astf(unsigned int* p, unsigned int v) {
  __hip_atomic_store(p, v, __ATOMIC_RELAXED, __HIP_MEMORY_SCOPE_AGENT);
}
__device__ __forceinline__ f32x4 mfma16(bf16x8 a, bf16x8 b, f32x4 c) {
  return __builtin_amdgcn_mfma_f32_16x16x32_bf16(a, b, c, 0, 0, 0);
}

// ---------------- fp32 -> bf16 conversion ----------------
__global__ __launch_bounds__(256) void cvt_kernel(const float* __restrict__ in,
                                                  us* __restrict__ out, int n) {
  const int stride = gridDim.x * blockDim.x * 4;
  for (int i = (blockIdx.x * blockDim.x + threadIdx.x) * 4; i < n; i += stride) {
    float4 v = *reinterpret_cast<const float4*>(in + i);
    ushort4 o;
    o.x = f2bf(v.x); o.y = f2bf(v.y); o.z = f2bf(v.z); o.w = f2bf(v.w);
    *reinterpret_cast<ushort4*>(out + i) = o;
  }
}

// ---------------- in-persist XP tile: one wave, one gate, 16 cols x 32 rows ----
// dst layout [gate(4)][bl(32)][jl(16)] bf16 (r9-proven)
__device__ __forceinline__ void xp_tile(const us* __restrict__ xb,
                                        const us* __restrict__ Wxb,
                                        us* dst, int tl, int b0,
                                        int j0, int gate, float biasv) {
  const int lane = threadIdx.x & 63;
  const int l15 = lane & 15;
  const int lk = (lane >> 4) * 8;
  const us* ap = xb + ((size_t)tl * Bn + b0 + l15) * INn + lk;
  const us* bp = Wxb + (size_t)(gate * 512 + j0 + l15) * INn + lk;
  f32x4 acc0 = {}, acc1 = {};
#pragma unroll
  for (int kt = 0; kt < 16; ++kt) {
    bf16x8 a0 = ld8(ap + kt * 32);
    bf16x8 a1 = ld8(ap + 16 * INn + kt * 32);
    bf16x8 bw = ld8(bp + kt * 32);
    acc0 = mfma16(a0, bw, acc0);
    acc1 = mfma16(a1, bw, acc1);
  }
#pragma unroll
  for (int r = 0; r < 4; ++r) {
    const int row = (lane >> 4) * 4 + r;
    dst[gate * 512 + row * 16 + l15] = f2bf(acc0[r] + biasv);
    dst[gate * 512 + (row + 16) * 16 + l15] = f2bf(acc1[r] + biasv);
  }
}

// gather 32 rows x 512 cols bf16 from LLC into swizzled LDS (r9-proven)
__device__ __forceinline__ void gather32(const us* src, us* dst, int b0) {
  const int lane = threadIdx.x & 63;
  const int w = threadIdx.x >> 6;
  const int c = (w << 3) + (lane & 7);
  const int r0 = (lane >> 3) << 2;
#pragma unroll
  for (int p = 0; p < 4; ++p) {
    const int rr = r0 + p;
    const us* s = src + (size_t)(b0 + rr) * Hn + c * 8;
    ull lo = ald8(s);
    ull hi = ald8(s + 4);
    char* d = (char*)dst + rr * 1024 + ((c * 16) ^ ((rr & 7) << 4));
    *(ull*)d = lo;
    *(ull*)(d + 8) = hi;
  }
}

// wave-local poll (8 waves, each covers its 4 gather-source blocks) (r9-proven)
__device__ __forceinline__ void poll_flags(const unsigned int* f, unsigned int ep,
                                           int jblk) {
  const int lane = threadIdx.x & 63;
  const int w = threadIdx.x >> 6;
  const int src = (w << 2) + ((lane & 7) >> 1);
  if (src == jblk) return;
  const unsigned int* p = f + src;
  while (aldf(p) < ep) __builtin_amdgcn_s_sleep(1);
}

__global__ __launch_bounds__(512, 1) void persist_kernel(
    const us* __restrict__ Whb,
    const us* __restrict__ Wghb,
    const us* __restrict__ Whdb,
    const us* __restrict__ Wgb,
    const us* __restrict__ xb,     // (Tc,256,512) bf16
    const us* __restrict__ Wxb,    // (2048,512) bf16
    const float* __restrict__ bx,
    const float* __restrict__ bh,
    const float* __restrict__ bgh,
    const float* __restrict__ bhd,
    const float* __restrict__ bg,
    us* __restrict__ hb0,          // 2 ping-pong slots of 256*512
    us* __restrict__ gb,
    float* __restrict__ g_master,
    const float* __restrict__ h0,
    const float* __restrict__ g0,
    float* __restrict__ hs,
    float* __restrict__ h_tail,
    float* __restrict__ g_tail,
    unsigned int* __restrict__ slab,  // per grp: [grp*64..+31]=FH, [+32..+63]=FG
    int t0, int Tc) {
  __shared__ us As_h[2][32 * 512];     // 2 x 32KB: h(t) / h(t-1) parity ping-pong
  __shared__ us As_B[32 * 512];        // 32KB: g (prologue/Y) or hd (X)
  __shared__ float pa[8][32][17];      // 17.4KB
  __shared__ us xp_ls[2][2048];        // 8KB XP double buffer

  const int tid = threadIdx.x;
  const int grp = blockIdx.x & 7;      // intra-XCD group (32 blocks, same XCD)
  const int jblk = blockIdx.x >> 3;
  const int j0 = jblk * 16;
  const int b0 = grp * 32;
  const int wv = tid >> 6;
  const int lane = tid & 63;
  const int l15 = lane & 15;
  const int lk = (lane >> 4) * 8;
  unsigned int* FH = slab + grp * 64;
  unsigned int* FG = slab + grp * 64 + 32;

  // ---- per-lane XP bias for this wave's gate ----
  const int gx = wv & 3;
  const int jx = j0 + l15;
  float bxp = bx[gx * 512 + jx];
  if (gx == 0) bxp += bh[jx] + bgh[jx];
  else if (gx == 1) bxp += bh[512 + jx] + bgh[512 + jx];
  else if (gx == 3) bxp += bh[1024 + jx] + bgh[1024 + jx];

  // ---- prologue XP: wv0-3 -> XP(t0) buf0, wv4-7 -> XP(t0+1) buf1 ----
  if (wv < 4) xp_tile(xb, Wxb, &xp_ls[0][0], 0, b0, j0, gx, bxp);
  else if (Tc > 1) xp_tile(xb, Wxb, &xp_ls[1][0], 1, b0, j0, gx, bxp);

  // ---- per-thread persistent state ----
  const int bl_e = tid >> 4, jl_e = tid & 15;
  const int j_e = j0 + jl_e;
  const size_t o_e = (size_t)(b0 + bl_e) * Hn + j_e;
  float h_m = (t0 == 0) ? h0[o_e] : hs[(size_t)(t0 - 1) * BnHn + o_e];
  float g_m = (t0 == 0) ? g0[o_e] : g_master[o_e];
  const float bz2 = bhd[j_e] + bg[j_e];
  const float br2 = bhd[512 + j_e] + bg[512 + j_e];
  const float bgc = bhd[1024 + j_e];
  const int xo = bl_e * 16 + jl_e;
  const int swzA = (l15 & 7) << 4;
  float z2p = 0.0f, r2p = 0.0f;

  // ---- prologue state seed from fp32 sources (r10-proven; no cross-block race) ----
  {
    const float* hsrc = (t0 == 0) ? h0 : hs + (size_t)(t0 - 1) * BnHn;
    const float* gsrc = (t0 == 0) ? g0 : g_master;
#pragma unroll
    for (int q = 0; q < 8; ++q) {
      const int f = tid + q * 512;
      const int rr = f >> 7, c4 = f & 127;
      const int byte = rr * 1024 + ((c4 * 8) ^ ((rr & 7) << 4));
      float4 hv = *reinterpret_cast<const float4*>(hsrc + (size_t)(b0 + rr) * Hn + c4 * 4);
      float4 gv = *reinterpret_cast<const float4*>(gsrc + (size_t)(b0 + rr) * Hn + c4 * 4);
      ull hu = (ull)f2bf(hv.x) | ((ull)f2bf(hv.y) << 16) | ((ull)f2bf(hv.z) << 32) |
               ((ull)f2bf(hv.w) << 48);
      ull gu = (ull)f2bf(gv.x) | ((ull)f2bf(gv.y) << 16) | ((ull)f2bf(gv.z) << 32) |
               ((ull)f2bf(gv.w) << 48);
      *reinterpret_cast<ull*>(reinterpret_cast<char*>(As_h[1]) + byte) = hu;  // h(t0-1)
      *reinterpret_cast<ull*>(reinterpret_cast<char*>(As_B) + byte) = gu;     // g(t0-1)
    }
  }
  __syncthreads();
  // ---- prologue GEMMs (all weights streamed from L2/LLC) ----
  {
    const us* As = (wv < 3) ? As_h[1] : As_B;
    const us* Wsel = (wv < 3) ? Whb : (wv < 6) ? Wghb : Wgb;
    const int off = (wv < 3) ? wv * 512 : (wv < 6) ? (wv - 3) * 512 : (wv - 6) * 512;
    const us* bp = Wsel + (size_t)(off + j0 + l15) * Hn + lk;
    f32x4 acc0 = {}, acc1 = {};
#pragma unroll
    for (int kt = 0; kt < 16; ++kt) {
      const int k2 = (kt * 32 + lk) * 2;
      const int abyte = k2 ^ swzA;
      bf16x8 a0 = *reinterpret_cast<const bf16x8*>(
          reinterpret_cast<const char*>(As) + l15 * 1024 + abyte);
      bf16x8 a1 = *reinterpret_cast<const bf16x8*>(
          reinterpret_cast<const char*>(As) + (16 + l15) * 1024 + abyte);
      bf16x8 bw = ld8(bp + kt * 32);
      acc0 = mfma16(a0, bw, acc0);
      acc1 = mfma16(a1, bw, acc1);
    }
#pragma unroll
    for (int r = 0; r < 4; ++r) {
      pa[wv][(lane >> 4) * 4 + r][l15] = acc0[r];
      pa[wv][16 + (lane >> 4) * 4 + r][l15] = acc1[r];
    }
  }
  __syncthreads();
  {  // h-update(t0); publish h(t0) only (hd is local now)
    const float z = sigm(bf2f(xp_ls[0][xo]) + pa[0][bl_e][jl_e] + pa[3][bl_e][jl_e]);
    const float r = sigm(bf2f(xp_ls[0][512 + xo]) + pa[1][bl_e][jl_e] + pa[4][bl_e][jl_e]);
    const float u = sigm(bf2f(xp_ls[0][1536 + xo]) + pa[2][bl_e][jl_e] + pa[5][bl_e][jl_e]);
    const float cand = tanh_f(bf2f(xp_ls[0][1024 + xo]) + r * h_m + u * g_m);
    const float hn = (1.0f - z) * h_m + z * cand;
    hs[(size_t)t0 * BnHn + o_e] = hn;
    if (t0 == Tn - 1) h_tail[o_e] = hn;
    const unsigned int hn_u = f2bf(hn);
    const unsigned int hn_hi = (unsigned int)__shfl_down((int)hn_u, 1);
    if ((jl_e & 1) == 0)
      ast4(hb0 + (size_t)((t0 + 1) & 1) * BnHn + o_e, hn_u | (hn_hi << 16));
    z2p = pa[6][bl_e][jl_e];
    r2p = pa[7][bl_e][jl_e];
    h_m = hn;
  }
  __syncthreads();                      // drains publish stores (vmcnt0)
  if (tid == 0) astf(FH + jblk, 1u);    // h(t0) ready

  // ================= MAIN LOOP =================
  for (int tt = 0; tt < Tc; ++tt) {
    const int t = t0 + tt;
    const int cur = tt & 1, prv = cur ^ 1;

    // -------- X(tt): gather h(t); local hd; GEMMs; g-update --------
    poll_flags(FH, (unsigned int)(tt + 1), jblk);
    gather32(hb0 + (size_t)((t + 1) & 1) * BnHn, As_h[cur], b0);  // h(t)
    __syncthreads();
#pragma unroll
    for (int q = 0; q < 8; ++q) {  // hd = h(t) - h(t-1), in swizzled layout
      const int f = tid + q * 512;
      const int rr = f >> 7, c8 = f & 127;
      const int byte = rr * 1024 + ((c8 * 8) ^ ((rr & 7) << 4));
      const ull va = *reinterpret_cast<const ull*>(reinterpret_cast<const char*>(As_h[cur]) + byte);
      const ull vb = *reinterpret_cast<const ull*>(reinterpret_cast<const char*>(As_h[prv]) + byte);
      ull o = 0;
#pragma unroll
      for (int i = 0; i < 4; ++i) {
        const float d = bf2f((us)(va >> (16 * i))) - bf2f((us)(vb >> (16 * i)));
        o |= (ull)f2bf(d) << (16 * i);
      }
      *reinterpret_cast<ull*>(reinterpret_cast<char*>(As_B) + byte) = o;
    }
    __syncthreads();
    if (wv < 3) {        // Wh · h(t) -> pa[0..2]  (for h-update(t+1))
      const us* bp = Whb + (size_t)(wv * 512 + j0 + l15) * Hn + lk;
      f32x4 acc0 = {}, acc1 = {};
#pragma unroll
      for (int kt = 0; kt < 16; ++kt) {
        const int k2 = (kt * 32 + lk) * 2;
        const int abyte = k2 ^ swzA;
        bf16x8 a0 = *reinterpret_cast<const bf16x8*>(
            reinterpret_cast<const char*>(As_h[cur]) + l15 * 1024 + abyte);
        bf16x8 a1 = *reinterpret_cast<const bf16x8*>(
            reinterpret_cast<const char*>(As_h[cur]) + (16 + l15) * 1024 + abyte);
        bf16x8 bw = ld8(bp + kt * 32);
        acc0 = mfma16(a0, bw, acc0);
        acc1 = mfma16(a1, bw, acc1);
      }
#pragma unroll
      for (int r = 0; r < 4; ++r) {
        pa[wv][(lane >> 4) * 4 + r][l15] = acc0[r];
        pa[wv][16 + (lane >> 4) * 4 + r][l15] = acc1[r];
      }
    } else if (wv < 6) {  // Whd · hd(t) -> pa[3..5]
      const us* bp = Whdb + (size_t)((wv - 3) * 512 + j0 + l15) * Hn + lk;
      f32x4 acc0 = {}, acc1 = {};
#pragma unroll
      for (int kt = 0; kt < 16; ++kt) {
        const int k2 = (kt * 32 + lk) * 2;
        const int abyte = k2 ^ swzA;
        bf16x8 a0 = *reinterpret_cast<const bf16x8*>(
            reinterpret_cast<const char*>(As_B) + l15 * 1024 + abyte);
        bf16x8 a1 = *reinterpret_cast<const bf16x8*>(
            reinterpret_cast<const char*>(As_B) + (16 + l15) * 1024 + abyte);
        bf16x8 bw = ld8(bp + kt * 32);
        acc0 = mfma16(a0, bw, acc0);
        acc1 = mfma16(a1, bw, acc1);
      }
#pragma unroll
      for (int r = 0; r < 4; ++r) {
        pa[wv][(lane >> 4) * 4 + r][l15] = acc0[r];
        pa[wv][16 + (lane >> 4) * 4 + r][l15] = acc1[r];
      }
    }
    __syncthreads();
    {  // g-update(t)
      const float z2 = sigm(pa[3][bl_e][jl_e] + z2p + bz2);
      const float r2 = sigm(pa[4][bl_e][jl_e] + r2p + br2);
      const float gc = tanh_f(pa[5][bl_e][jl_e] + bgc + r2 * g_m);
      const float gn = (1.0f - z2) * g_m + z2 * gc;
      g_m = gn;
      if (t == Tn - 1) g_tail[o_e] = gn;
      const unsigned int gn_u = f2bf(gn);
      const unsigned int gn_hi = (unsigned int)__shfl_down((int)gn_u, 1);
      if ((jl_e & 1) == 0) ast4(gb + o_e, gn_u | (gn_hi << 16));
    }
    __syncthreads();
    if (tid == 0) astf(FG + jblk, (unsigned int)(tt + 1));

    if (tt + 1 >= Tc) break;

    // -------- Y(tt): gather g(t); GEMMs; h-update(t+1); idle waves do XP(t+2) ----
    if (wv < 4) {
      {  // poll: 4 waves cover 8 sources each
        const int src = (wv << 3) + (lane & 7);
        if (src != jblk) {
          const unsigned int* p = FG + src;
          while (aldf(p) < (unsigned int)(tt + 1)) __builtin_amdgcn_s_sleep(1);
        }
      }
      for (int p = 0; p < 8; ++p) {  // gather g: 256 threads x 8 chunks
        const int idx = tid + p * 256;
        const int rr = idx >> 6, c = idx & 63;
        const us* s = gb + (size_t)(b0 + rr) * Hn + c * 8;
        ull lo = ald8(s);
        ull hi = ald8(s + 4);
        char* d = (char*)As_B + rr * 1024 + ((c * 16) ^ ((rr & 7) << 4));
        *(ull*)d = lo;
        *(ull*)(d + 8) = hi;
      }
    } else if (tt + 2 < Tc) {  // XP(t+2) into buf[tt&1] (dead since h-update(t))
      xp_tile(xb, Wxb, &xp_ls[tt & 1][0], tt + 2, b0, j0, gx, bxp);
    }
    __syncthreads();
    if (wv < 3) {  // Wgh·g -> pa[3..5]
      const us* bp = Wghb + (size_t)(wv * 512 + j0 + l15) * Hn + lk;
      f32x4 acc0 = {}, acc1 = {};
#pragma unroll
      for (int kt = 0; kt < 16; ++kt) {
        const int k2 = (kt * 32 + lk) * 2;
        const int abyte = k2 ^ swzA;
        bf16x8 a0 = *reinterpret_cast<const bf16x8*>(
            reinterpret_cast<const char*>(As_B) + l15 * 1024 + abyte);
        bf16x8 a1 = *reinterpret_cast<const bf16x8*>(
            reinterpret_cast<const char*>(As_B) + (16 + l15) * 1024 + abyte);
        bf16x8 bw = ld8(bp + kt * 32);
        acc0 = mfma16(a0, bw, acc0);
        acc1 = mfma16(a1, bw, acc1);
      }
#pragma unroll
      for (int r = 0; r < 4; ++r) {
        pa[3 + wv][(lane >> 4) * 4 + r][l15] = acc0[r];
        pa[3 + wv][16 + (lane >> 4) * 4 + r][l15] = acc1[r];
      }
    } else if (wv == 3) {  // Wg·g both gates -> pa[6], pa[7]
      const us* bp0 = Wgb + (size_t)(j0 + l15) * Hn + lk;
      const us* bp1 = Wgb + (size_t)(512 + j0 + l15) * Hn + lk;
      f32x4 a00 = {}, a01 = {}, a10 = {}, a11 = {};
#pragma unroll
      for (int kt = 0; kt < 16; ++kt) {
        const int k2 = (kt * 32 + lk) * 2;
        const int abyte = k2 ^ swzA;
        bf16x8 a0 = *reinterpret_cast<const bf16x8*>(
            reinterpret_cast<const char*>(As_B) + l15 * 1024 + abyte);
        bf16x8 a1 = *reinterpret_cast<const bf16x8*>(
            reinterpret_cast<const char*>(As_B) + (16 + l15) * 1024 + abyte);
        bf16x8 w0 = ld8(bp0 + kt * 32);
        bf16x8 w1 = ld8(bp1 + kt * 32);
        a00 = mfma16(a0, w0, a00);
        a10 = mfma16(a1, w0, a10);
        a01 = mfma16(a0, w1, a01);
        a11 = mfma16(a1, w1, a11);
      }
#pragma unroll
      for (int r = 0; r < 4; ++r) {
        pa[6][(lane >> 4) * 4 + r][l15] = a00[r];
        pa[6][16 + (lane >> 4) * 4 + r][l15] = a10[r];
        pa[7][(lane >> 4) * 4 + r][l15] = a01[r];
        pa[7][16 + (lane >> 4) * 4 + r][l15] = a11[r];
      }
    }
    __syncthreads();
    {  // h-update(t+1); publish h(t+1) only
      const int xb_ = (tt + 1) & 1;
      const float z = sigm(bf2f(xp_ls[xb_][xo]) + pa[0][bl_e][jl_e] + pa[3][bl_e][jl_e]);
      const float r = sigm(bf2f(xp_ls[xb_][512 + xo]) + pa[1][bl_e][jl_e] + pa[4][bl_e][jl_e]);
      const float u = sigm(bf2f(xp_ls[xb_][1536 + xo]) + pa[2][bl_e][jl_e] + pa[5][bl_e][jl_e]);
      const float cand = tanh_f(bf2f(xp_ls[xb_][1024 + xo]) + r * h_m + u * g_m);
      const float hn = (1.0f - z) * h_m + z * cand;
      hs[(size_t)(t + 1) * BnHn + o_e] = hn;
      if (t + 1 == Tn - 1) h_tail[o_e] = hn;
      const unsigned int hn_u = f2bf(hn);
      const unsigned int hn_hi = (unsigned int)__shfl_down((int)hn_u, 1);
      if ((jl_e & 1) == 0)
        ast4(hb0 + (size_t)(t & 1) * BnHn + o_e, hn_u | (hn_hi << 16));
      z2p = pa[6][bl_e][jl_e];
      r2p = pa[7][bl_e][jl_e];
      h_m = hn;
    }
    __syncthreads();
    if (tid == 0) astf(FH + jblk, (unsigned int)(tt + 2));
  }
  g_master[o_e] = g_m;
}

// ---------------- host ----------------
extern "C" void kernel_launch(void* const* d_in, const int* in_sizes, int n_in,
                              void* d_out, int out_size, void* d_ws, size_t ws_size,
                              hipStream_t stream) {
  const float* x   = (const float*)d_in[0];
  const float* h0  = (const float*)d_in[1];
  const float* g0  = (const float*)d_in[2];
  const float* Wx  = (const float*)d_in[3];
  const float* bx  = (const float*)d_in[4];
  const float* Wh  = (const float*)d_in[5];
  const float* bh  = (const float*)d_in[6];
  const float* Wgh = (const float*)d_in[7];
  const float* bgh = (const float*)d_in[8];
  const float* Whd = (const float*)d_in[9];
  const float* bhd = (const float*)d_in[10];
  const float* Wg  = (const float*)d_in[11];
  const float* bg  = (const float*)d_in[12];

  char* ws = (char*)d_ws;
  us* Whb  = (us*)(ws + 0);                // 1536x512
  us* Wghb = (us*)(ws + 1572864);
  us* Whdb = (us*)(ws + 3145728);
  us* Wgb  = (us*)(ws + 4718592);          // 1024x512
  us* Wxb  = (us*)(ws + 5767168);          // 2048x512
  us* hb0  = (us*)(ws + 7864320);          // 2 x 256x512 bf16 (parity slots)
  us* gb_  = (us*)(ws + 8388608);          // 256x512 bf16
  float* g_master     = (float*)(ws + 8650752);   // 256x512 f32
  unsigned int* flags = (unsigned int*)(ws + 9175040);  // 2KB
  const size_t FIXED = 9177088ULL;

  int Tc = 512;   // single launch if ws allows
  while (Tc > 1 && FIXED + (size_t)Tc * 262144ULL > ws_size) Tc >>= 1;
  us* xb = (us*)(ws + FIXED);  // (Tc,256,512) bf16

  float* hs = (float*)d_out;
  float* h_tail = hs + (size_t)Tn * Bn * Hn;
  float* g_tail = h_tail + (size_t)Bn * Hn;

  cvt_kernel<<<dim3(512), 256, 0, stream>>>(Wh, Whb, 1536 * 512);
  cvt_kernel<<<dim3(512), 256, 0, stream>>>(Wgh, Wghb, 1536 * 512);
  cvt_kernel<<<dim3(512), 256, 0, stream>>>(Whd, Whdb, 1536 * 512);
  cvt_kernel<<<dim3(512), 256, 0, stream>>>(Wg, Wgb, 1024 * 512);
  cvt_kernel<<<dim3(512), 256, 0, stream>>>(Wx, Wxb, 2048 * 512);

  const int nChunks = Tn / Tc;
  for (int c = 0; c < nChunks; ++c) {
    const int t0 = c * Tc;
    hipMemsetAsync(flags, 0, 2048, stream);
    cvt_kernel<<<dim3(2048), 256, 0, stream>>>(x + (size_t)t0 * Bn * INn, xb,
                                               Tc * Bn * INn);
    persist_kernel<<<dim3(256), dim3(TPB), 0, stream>>>(
        Whb, Wghb, Whdb, Wgb, xb, Wxb, bx, bh, bgh, bhd, bg, hb0, gb_,
        g_master, h0, g0, hs, h_tail, g_tail, flags, t0, Tc);
  }
}

// Round 14
// 10073.664 us; speedup vs baseline: 3.0504x; 1.0366x over previous
//
#include <hip/hip_runtime.h>

#define Tn 512
#define Bn 256
#define Hn 512
#define INn 512
#define TPB 512
#define RG 16              // batch rows per group
#define CB 32              // output cols per block
#define BnHn (Bn * Hn)

typedef __attribute__((ext_vector_type(8))) short bf16x8;
typedef __attribute__((ext_vector_type(4))) float f32x4;
typedef unsigned long long ull;
typedef unsigned short us;

__device__ __forceinline__ us f2bf(float f) {
  unsigned int u = __float_as_uint(f);
  return (us)((u + 0x7fffu + ((u >> 16) & 1u)) >> 16);
}
__device__ __forceinline__ float bf2f(us u) {
  return __uint_as_float(((unsigned int)u) << 16);
}
__device__ __forceinline__ float sigm(float x) { return 1.0f / (1.0f + __expf(-x)); }
__device__ __forceinline__ float tanh_f(float x) { return 2.0f / (1.0f + __expf(-2.0f * x)) - 1.0f; }
__device__ __forceinline__ bf16x8 ld8(const us* p) { return *reinterpret_cast<const bf16x8*>(p); }

// ---- agent-scope (LLC) relaxed ops — proven r3/r4/r8/r9/r13 (intra-XCD groups) ----
__device__ __forceinline__ ull ald8(const us* p) {
  return __hip_atomic_load((const ull*)p, __ATOMIC_RELAXED, __HIP_MEMORY_SCOPE_AGENT);
}
__device__ __forceinline__ void ast4(us* p, unsigned int v) {
  __hip_atomic_store((unsigned int*)p, v, __ATOMIC_RELAXED, __HIP_MEMORY_SCOPE_AGENT);
}
__device__ __forceinline__ unsigned int aldf(const unsigned int* p) {
  return __hip_atomic_load(p, __ATOMIC_RELAXED, __HIP_MEMORY_SCOPE_AGENT);
}
__device__ __forceinline__ void astf(unsigned int* p, unsigned int v) {
  __hip_atomic_store(p, v, __ATOMIC_RELAXED, __HIP_MEMORY_SCOPE_AGENT);
}
__device__ __forceinline__ f32x4 mfma16(bf16x8 a, bf16x8 b, f32x4 c) {
  return __builtin_amdgcn_mfma_f32_16x16x32_bf16(a, b, c, 0, 0, 0);
}

// ---------------- fp32 -> bf16 conversion ----------------
__global__ __launch_bounds__(256) void cvt_kernel(const float* __restrict__ in,
                                                  us* __restrict__ out, int n) {
  const int stride = gridDim.x * blockDim.x * 4;
  for (int i = (blockIdx.x * blockDim.x + threadIdx.x) * 4; i < n; i += stride) {
    float4 v = *reinterpret_cast<const float4*>(in + i);
    ushort4 o;
    o.x = f2bf(v.x); o.y = f2bf(v.y); o.z = f2bf(v.z); o.w = f2bf(v.w);
    *reinterpret_cast<ushort4*>(out + i) = o;
  }
}

// ---- one 16x16 state tile from swizzled-LDS A (16 rows) and weight src ----
// Wsrc: either global (stride Hn, row = wbase+l15) or LDS Wh_l (handled by caller flag)
__device__ __forceinline__ void tile_state_g(const us* As, const us* W, int wbase,
                                             float (*po)[CB + 1], int dcol, int lane) {
  const int l15 = lane & 15;
  const int lk = (lane >> 4) * 8;
  const us* wp = W + (size_t)(wbase + l15) * Hn + lk;
  f32x4 acc = {};
#pragma unroll
  for (int kt = 0; kt < 16; ++kt) {
    const int k2 = (kt * 32 + lk) * 2;
    bf16x8 a = *reinterpret_cast<const bf16x8*>(
        reinterpret_cast<const char*>(As) + l15 * 1024 + (k2 ^ ((l15 & 7) << 4)));
    acc = mfma16(a, ld8(wp + kt * 32), acc);
  }
  const int r0 = (lane >> 4) * 4;
#pragma unroll
  for (int r = 0; r < 4; ++r) po[r0 + r][dcol + l15] = acc[r];
}

__device__ __forceinline__ void tile_state_l(const us* As, const us* Wl, int wrow0,
                                             float (*po)[CB + 1], int dcol, int lane) {
  const int l15 = lane & 15;
  const int lk = (lane >> 4) * 8;
  const int wrow = wrow0 + l15;
  f32x4 acc = {};
#pragma unroll
  for (int kt = 0; kt < 16; ++kt) {
    const int k2 = (kt * 32 + lk) * 2;
    bf16x8 a = *reinterpret_cast<const bf16x8*>(
        reinterpret_cast<const char*>(As) + l15 * 1024 + (k2 ^ ((l15 & 7) << 4)));
    bf16x8 bw = *reinterpret_cast<const bf16x8*>(
        reinterpret_cast<const char*>(Wl) + wrow * 1024 + (k2 ^ ((wrow & 7) << 4)));
    acc = mfma16(a, bw, acc);
  }
  const int r0 = (lane >> 4) * 4;
#pragma unroll
  for (int r = 0; r < 4; ++r) po[r0 + r][dcol + l15] = acc[r];
}

// ---- one 16x16 XP tile (bias-folded, bf16 out [gate][16][32]) ----
__device__ __forceinline__ void tile_xp(const us* __restrict__ xb, const us* __restrict__ Wxb,
                                        const float* __restrict__ bx, const float* __restrict__ bh,
                                        const float* __restrict__ bgh, us* xpdst, int tl,
                                        int b0, int j0, int gate, int dcol, int lane) {
  const int l15 = lane & 15;
  const int lk = (lane >> 4) * 8;
  const us* ap = xb + ((size_t)tl * Bn + b0 + l15) * INn + lk;
  const us* wp = Wxb + (size_t)(gate * 512 + j0 + dcol + l15) * INn + lk;
  f32x4 acc = {};
#pragma unroll
  for (int kt = 0; kt < 16; ++kt)
    acc = mfma16(ld8(ap + kt * 32), ld8(wp + kt * 32), acc);
  const int col = j0 + dcol + l15;
  float bias = bx[gate * 512 + col];
  if (gate == 0) bias += bh[col] + bgh[col];
  else if (gate == 1) bias += bh[512 + col] + bgh[512 + col];
  else if (gate == 3) bias += bh[1024 + col] + bgh[1024 + col];
  const int r0 = (lane >> 4) * 4;
#pragma unroll
  for (int r = 0; r < 4; ++r)
    xpdst[gate * 512 + (r0 + r) * CB + dcol + l15] = f2bf(acc[r] + bias);
}

// gather RG=16 rows x 512 cols bf16 from LLC into swizzled LDS (32B/thread)
__device__ __forceinline__ void gather16(const us* src, us* dst, int b0) {
  const int rr = threadIdx.x >> 5;
  const int c16 = threadIdx.x & 31;
  const us* s = src + (size_t)(b0 + rr) * Hn + c16 * 16;
  char* d = (char*)dst + rr * 1024;
  const int swz = (rr & 7) << 4;
#pragma unroll
  for (int q = 0; q < 4; ++q)
    *(ull*)(d + ((c16 * 32 + q * 8) ^ swz)) = ald8(s + q * 4);
}

// poll all 16 producer flags of this group (every wave)
__device__ __forceinline__ void poll16(const unsigned int* f, unsigned int ep) {
  if ((threadIdx.x & 63) < 16) {
    const unsigned int* p = f + (threadIdx.x & 63);
    while (aldf(p) < ep) __builtin_amdgcn_s_sleep(1);
  }
  __builtin_amdgcn_sched_barrier(0);
  asm volatile("" ::: "memory");
}

// ---------------- persistent recurrence ----------------
// 256 blocks: grp = blockIdx&15 (16 b-rows; group-mates all at blockIdx%8 ==
// grp%8 -> same XCD, proven intra-XCD exchange), jblk = blockIdx>>4 (32 cols).
// Wh slice in LDS; Whd/Wgh/Wg streamed (phase-active set ~2.5MB, L2-fits, r9).
// hd computed in place of h(t-1); g shares the prv LDS slot. 2 gathers/step.
__global__ __launch_bounds__(512, 1) void persist_kernel(
    const us* __restrict__ Whb, const us* __restrict__ Wghb,
    const us* __restrict__ Whdb, const us* __restrict__ Wgb,
    const us* __restrict__ xb, const us* __restrict__ Wxb,
    const float* __restrict__ bx, const float* __restrict__ bh,
    const float* __restrict__ bgh, const float* __restrict__ bhd,
    const float* __restrict__ bg,
    us* __restrict__ hb0,          // 2 parity slots of 256*512 (h(t) in slot (t+1)&1)
    us* __restrict__ gb,           // single slot (flag-chain ordered, r13-proven)
    float* __restrict__ g_master,
    const float* __restrict__ h0, const float* __restrict__ g0,
    float* __restrict__ hs, float* __restrict__ h_tail, float* __restrict__ g_tail,
    unsigned int* __restrict__ slab,  // per grp: [grp*32..+15]=FH, [+16..+31]=FG
    int t0, int Tc) {
  __shared__ us Wh_l[96 * 512];        // 96KB swizzled Wh (z,r,u) x 32-col slice
  __shared__ us As_h[2][RG * 512];     // 2 x 16KB: h parity; prv slot doubles as hd/g
  __shared__ float pa[8][RG][CB + 1];  // 16.5KB
  __shared__ us xp_ls[2][4 * RG * CB]; // 2 x 4KB

  const int tid = threadIdx.x;
  const int grp = blockIdx.x & 15;
  const int jblk = blockIdx.x >> 4;
  const int j0 = jblk * CB;
  const int b0 = grp * RG;
  const int wv = tid >> 6;
  const int lane = tid & 63;
  unsigned int* FH = slab + grp * 32;
  unsigned int* FG = FH + 16;

  // ---- stage Wh slice (96 rows: gate*32+col) into LDS, swizzled ----
  for (int i = tid; i < 96 * 64; i += TPB) {
    const int rr = i >> 6, cw = i & 63;
    const int grow = (rr >> 5) * 512 + j0 + (rr & 31);
    const int byte = rr * 1024 + ((cw * 16) ^ ((rr & 7) << 4));
    *reinterpret_cast<uint4*>(reinterpret_cast<char*>(Wh_l) + byte) =
        *reinterpret_cast<const uint4*>(Whb + (size_t)grow * 512 + cw * 8);
  }

  // ---- per-thread persistent state (1 elem/thread: 16 rows x 32 cols) ----
  const int bl_e = tid >> 5;
  const int jl_e = tid & 31;
  const int j_e = j0 + jl_e;
  const size_t o_e = (size_t)(b0 + bl_e) * Hn + j_e;
  float h_m = (t0 == 0) ? h0[o_e] : hs[(size_t)(t0 - 1) * BnHn + o_e];
  float g_m = (t0 == 0) ? g0[o_e] : g_master[o_e];
  const float bz2 = bhd[j_e] + bg[j_e];
  const float br2 = bhd[512 + j_e] + bg[512 + j_e];
  const float bgc = bhd[1024 + j_e];
  const int xo = bl_e * CB + jl_e;
  float z2p = 0.0f, r2p = 0.0f;

  // ---- prologue XP: 16 tiles -> buf0 = XP(t0), buf1 = XP(t0+1) ----
  for (int idx = wv; idx < 16; idx += 8) {
    const int tl = idx >> 3;
    if (tl < Tc) {
      const int u = idx & 7;
      tile_xp(xb, Wxb, bx, bh, bgh, xp_ls[tl], tl, b0, j0, u >> 1, (u & 1) * 16, lane);
    }
  }
  // ---- prologue seeds: h(t0-1) -> As_h[1], g(t0-1) -> As_h[0], from fp32 ----
  {
    const float* hsrc = (t0 == 0) ? h0 : hs + (size_t)(t0 - 1) * BnHn;
    const float* gsrc = (t0 == 0) ? g0 : g_master;
#pragma unroll
    for (int q = 0; q < 4; ++q) {
      const int f = tid + q * 512;
      const int rr = f >> 7, c4 = f & 127;
      const int byte = rr * 1024 + ((c4 * 8) ^ ((rr & 7) << 4));
      float4 hv = *reinterpret_cast<const float4*>(hsrc + (size_t)(b0 + rr) * Hn + c4 * 4);
      float4 gv = *reinterpret_cast<const float4*>(gsrc + (size_t)(b0 + rr) * Hn + c4 * 4);
      ull hu = (ull)f2bf(hv.x) | ((ull)f2bf(hv.y) << 16) | ((ull)f2bf(hv.z) << 32) |
               ((ull)f2bf(hv.w) << 48);
      ull gu = (ull)f2bf(gv.x) | ((ull)f2bf(gv.y) << 16) | ((ull)f2bf(gv.z) << 32) |
               ((ull)f2bf(gv.w) << 48);
      *reinterpret_cast<ull*>(reinterpret_cast<char*>(As_h[1]) + byte) = hu;
      *reinterpret_cast<ull*>(reinterpret_cast<char*>(As_h[0]) + byte) = gu;
    }
  }
  __syncthreads();
  // ---- prologue GEMMs: Wh(LDS) 6, Wgh 6, Wg 4 ----
  for (int idx = wv; idx < 16; idx += 8) {
    if (idx < 6)
      tile_state_l(As_h[1], Wh_l, (idx >> 1) * 32 + (idx & 1) * 16, pa[idx >> 1],
                   (idx & 1) * 16, lane);
    else if (idx < 12) {
      const int i = idx - 6;
      tile_state_g(As_h[0], Wghb, (i >> 1) * 512 + j0 + (i & 1) * 16, pa[3 + (i >> 1)],
                   (i & 1) * 16, lane);
    } else {
      const int i = idx - 12;
      tile_state_g(As_h[0], Wgb, (i >> 1) * 512 + j0 + (i & 1) * 16, pa[6 + (i >> 1)],
                   (i & 1) * 16, lane);
    }
  }
  __syncthreads();
  {  // h-update(t0) + publish into hb0[(t0+1)&1]
    const float z = sigm(bf2f(xp_ls[0][xo]) + pa[0][bl_e][jl_e] + pa[3][bl_e][jl_e]);
    const float r = sigm(bf2f(xp_ls[0][512 + xo]) + pa[1][bl_e][jl_e] + pa[4][bl_e][jl_e]);
    const float u = sigm(bf2f(xp_ls[0][1536 + xo]) + pa[2][bl_e][jl_e] + pa[5][bl_e][jl_e]);
    const float cand = tanh_f(bf2f(xp_ls[0][1024 + xo]) + r * h_m + u * g_m);
    const float hn = (1.0f - z) * h_m + z * cand;
    hs[(size_t)t0 * BnHn + o_e] = hn;
    if (t0 == Tn - 1) h_tail[o_e] = hn;
    const unsigned int hn_u = f2bf(hn);
    const unsigned int hn_hi = (unsigned int)__shfl_down((int)hn_u, 1);
    if ((jl_e & 1) == 0)
      ast4(hb0 + (size_t)((t0 + 1) & 1) * BnHn + o_e, hn_u | (hn_hi << 16));
    z2p = pa[6][bl_e][jl_e];
    r2p = pa[7][bl_e][jl_e];
    h_m = hn;
  }
  __syncthreads();                      // drains publish stores (vmcnt0)
  if (tid == 0) astf(FH + jblk, 1u);

  // ================= MAIN LOOP =================
  for (int tt = 0; tt < Tc; ++tt) {
    const int t = t0 + tt;
    const int cur = tt & 1, prv = cur ^ 1;

    // -------- X(tt): gather h(t) -> As_h[cur]; hd in place of As_h[prv];
    //          GEMMs (Wh, Whd, XP g0/g1); g-update --------
    poll16(FH, (unsigned int)(tt + 1));
    gather16(hb0 + (size_t)((t + 1) & 1) * BnHn, As_h[cur], b0);
    __syncthreads();
    {  // hd = h(t) - h(t-1), written over h(t-1)
      const int rr = tid >> 5, c16 = tid & 31;
      const int swz = (rr & 7) << 4;
      char* pc = (char*)As_h[cur] + rr * 1024;
      char* pp = (char*)As_h[prv] + rr * 1024;
#pragma unroll
      for (int q = 0; q < 4; ++q) {
        const int byte = (c16 * 32 + q * 8) ^ swz;
        const ull va = *(const ull*)(pc + byte);
        const ull vb = *(const ull*)(pp + byte);
        ull o = 0;
#pragma unroll
        for (int i = 0; i < 4; ++i) {
          const float d = bf2f((us)(va >> (16 * i))) - bf2f((us)(vb >> (16 * i)));
          o |= (ull)f2bf(d) << (16 * i);
        }
        *(ull*)(pp + byte) = o;
      }
    }
    __syncthreads();
    for (int idx = wv; idx < 16; idx += 8) {  // Wh 6 (LDS), Whd 6, XP(t+2) g0/g1 4
      if (idx < 6)
        tile_state_l(As_h[cur], Wh_l, (idx >> 1) * 32 + (idx & 1) * 16, pa[idx >> 1],
                     (idx & 1) * 16, lane);
      else if (idx < 12) {
        const int i = idx - 6;
        tile_state_g(As_h[prv], Whdb, (i >> 1) * 512 + j0 + (i & 1) * 16, pa[3 + (i >> 1)],
                     (i & 1) * 16, lane);
      } else if (tt + 2 < Tc) {
        const int u = idx - 12;
        tile_xp(xb, Wxb, bx, bh, bgh, xp_ls[cur], tt + 2, b0, j0, u >> 1, (u & 1) * 16, lane);
      }
    }
    __syncthreads();
    {  // g-update(t) + publish
      const float z2 = sigm(pa[3][bl_e][jl_e] + z2p + bz2);
      const float r2 = sigm(pa[4][bl_e][jl_e] + r2p + br2);
      const float gc = tanh_f(pa[5][bl_e][jl_e] + bgc + r2 * g_m);
      g_m = (1.0f - z2) * g_m + z2 * gc;
      const unsigned int gn_u = f2bf(g_m);
      const unsigned int gn_hi = (unsigned int)__shfl_down((int)gn_u, 1);
      if ((jl_e & 1) == 0) ast4(gb + o_e, gn_u | (gn_hi << 16));
    }
    __syncthreads();
    if (tid == 0) astf(FG + jblk, (unsigned int)(tt + 1));
    if (t == Tn - 1) g_tail[o_e] = g_m;
    if (tt + 1 >= Tc) break;

    // -------- Y(tt): gather g(t) -> As_h[prv]; GEMMs (Wgh, Wg, XP g2/g3);
    //          h-update(t+1) --------
    poll16(FG, (unsigned int)(tt + 1));
    gather16(gb, As_h[prv], b0);
    __syncthreads();
    for (int idx = wv; idx < 14; idx += 8) {  // Wgh 6, Wg 4, XP(t+2) g2/g3 4
      if (idx < 6)
        tile_state_g(As_h[prv], Wghb, (idx >> 1) * 512 + j0 + (idx & 1) * 16,
                     pa[3 + (idx >> 1)], (idx & 1) * 16, lane);
      else if (idx < 10) {
        const int i = idx - 6;
        tile_state_g(As_h[prv], Wgb, (i >> 1) * 512 + j0 + (i & 1) * 16, pa[6 + (i >> 1)],
                     (i & 1) * 16, lane);
      } else if (tt + 2 < Tc) {
        const int u = idx - 10;
        tile_xp(xb, Wxb, bx, bh, bgh, xp_ls[cur], tt + 2, b0, j0, 2 + (u >> 1),
                (u & 1) * 16, lane);
      }
    }
    __syncthreads();
    {  // h-update(t+1) + publish into hb0[t&1]
      const int xb_ = (tt + 1) & 1;
      const float z = sigm(bf2f(xp_ls[xb_][xo]) + pa[0][bl_e][jl_e] + pa[3][bl_e][jl_e]);
      const float r = sigm(bf2f(xp_ls[xb_][512 + xo]) + pa[1][bl_e][jl_e] + pa[4][bl_e][jl_e]);
      const float u = sigm(bf2f(xp_ls[xb_][1536 + xo]) + pa[2][bl_e][jl_e] + pa[5][bl_e][jl_e]);
      const float cand = tanh_f(bf2f(xp_ls[xb_][1024 + xo]) + r * h_m + u * g_m);
      const float hn = (1.0f - z) * h_m + z * cand;
      hs[(size_t)(t + 1) * BnHn + o_e] = hn;
      if (t + 1 == Tn - 1) h_tail[o_e] = hn;
      const unsigned int hn_u = f2bf(hn);
      const unsigned int hn_hi = (unsigned int)__shfl_down((int)hn_u, 1);
      if ((jl_e & 1) == 0)
        ast4(hb0 + (size_t)(t & 1) * BnHn + o_e, hn_u | (hn_hi << 16));
      z2p = pa[6][bl_e][jl_e];
      r2p = pa[7][bl_e][jl_e];
      h_m = hn;
    }
    __syncthreads();
    if (tid == 0) astf(FH + jblk, (unsigned int)(tt + 2));
  }
  g_master[o_e] = g_m;
}

// ---------------- host ----------------
extern "C" void kernel_launch(void* const* d_in, const int* in_sizes, int n_in,
                              void* d_out, int out_size, void* d_ws, size_t ws_size,
                              hipStream_t stream) {
  const float* x   = (const float*)d_in[0];
  const float* h0  = (const float*)d_in[1];
  const float* g0  = (const float*)d_in[2];
  const float* Wx  = (const float*)d_in[3];
  const float* bx  = (const float*)d_in[4];
  const float* Wh  = (const float*)d_in[5];
  const float* bh  = (const float*)d_in[6];
  const float* Wgh = (const float*)d_in[7];
  const float* bgh = (const float*)d_in[8];
  const float* Whd = (const float*)d_in[9];
  const float* bhd = (const float*)d_in[10];
  const float* Wg  = (const float*)d_in[11];
  const float* bg  = (const float*)d_in[12];

  char* ws = (char*)d_ws;
  us* Whb  = (us*)(ws + 0);                // 1536x512
  us* Wghb = (us*)(ws + 1572864);
  us* Whdb = (us*)(ws + 3145728);
  us* Wgb  = (us*)(ws + 4718592);          // 1024x512
  us* Wxb  = (us*)(ws + 5767168);          // 2048x512
  us* hb0  = (us*)(ws + 7864320);          // 2 x 256x512 bf16 (parity slots)
  us* gb_  = (us*)(ws + 8388608);          // 256x512 bf16
  float* g_master     = (float*)(ws + 8650752);   // 256x512 f32
  unsigned int* flags = (unsigned int*)(ws + 9175040);  // 2KB
  const size_t FIXED = 9177088ULL;

  int Tc = 512;   // single launch if ws allows
  while (Tc > 1 && FIXED + (size_t)Tc * 262144ULL > ws_size) Tc >>= 1;
  us* xb = (us*)(ws + FIXED);  // (Tc,256,512) bf16

  float* hs = (float*)d_out;
  float* h_tail = hs + (size_t)Tn * Bn * Hn;
  float* g_tail = h_tail + (size_t)Bn * Hn;

  cvt_kernel<<<dim3(512), 256, 0, stream>>>(Wh, Whb, 1536 * 512);
  cvt_kernel<<<dim3(512), 256, 0, stream>>>(Wgh, Wghb, 1536 * 512);
  cvt_kernel<<<dim3(512), 256, 0, stream>>>(Whd, Whdb, 1536 * 512);
  cvt_kernel<<<dim3(512), 256, 0, stream>>>(Wg, Wgb, 1024 * 512);
  cvt_kernel<<<dim3(512), 256, 0, stream>>>(Wx, Wxb, 2048 * 512);

  const int nChunks = Tn / Tc;
  for (int c = 0; c < nChunks; ++c) {
    const int t0 = c * Tc;
    hipMemsetAsync(flags, 0, 2048, stream);
    cvt_kernel<<<dim3(2048), 256, 0, stream>>>(x + (size_t)t0 * Bn * INn, xb,
                                               Tc * Bn * INn);
    persist_kernel<<<dim3(256), dim3(TPB), 0, stream>>>(
        Whb, Wghb, Whdb, Wgb, xb, Wxb, bx, bh, bgh, bhd, bg, hb0, gb_,
        g_master, h0, g0, hs, h_tail, g_tail, flags, t0, Tc);
  }
}